// Round 1
// baseline (2468.523 us; speedup 1.0000x reference)
//
#include <hip/hip_runtime.h>
#include <math.h>

// Problem constants
#define NB   128   // batch
#define CI_  3
#define HI_  128
#define G_   12
#define HG_  16
#define HIDLIN_ 512

// ---------------------------------------------------------------------------
// Kernel 1: fused conv1(3->32) + relu + conv2(32->32) + relu + maxpool4
// grid (16 tiles, 128 batch), 256 threads.
// Per block: pooled 8x8 tile => conv2 region 32x32 => conv1 tile 34x34 (halo 1)
// => image tile 36x36 (halo 2).
// conv1 tile lives in LDS, 8 channels at a time (4 ci-phases), swizzled:
//   addr(ch,y,x) = ch*1164 + y*34 + (y>>2) + x   (2-way banks for conv2 reads)
// conv2: thread = (wave=oc-group, lane=pooled cell); acc[2 passes][4oc][16vals].
// ---------------------------------------------------------------------------
__global__ __launch_bounds__(256, 2)
void k_conv12(const float* __restrict__ img, const float* __restrict__ w1,
              const float* __restrict__ b1, const float* __restrict__ w2,
              const float* __restrict__ b2, float* __restrict__ P1)
{
    __shared__ float simg[3 * 36 * 36];   // 15552 B
    __shared__ float c1t[8 * 1164];       // 37248 B  (total 52.8 KB)

    const int t  = threadIdx.x;
    const int bt = blockIdx.x;            // 0..15
    const int b  = blockIdx.y;
    const int ty = bt >> 2, tx = bt & 3;
    const int oy = ty * 32, ox = tx * 32;

    // stage image tile [3][36][36], origin (oy-2, ox-2), zero-padded
    for (int i = t; i < 3 * 36 * 36; i += 256) {
        const int ci = i / 1296, r = i - ci * 1296;
        const int yy = r / 36, xx = r - yy * 36;
        const int gy = oy - 2 + yy, gx = ox - 2 + xx;
        float v = 0.f;
        if ((unsigned)gy < 128u && (unsigned)gx < 128u)
            v = img[((b * 3 + ci) * 128 + gy) * 128 + gx];
        simg[i] = v;
    }
    __syncthreads();

    const int wv   = t >> 6;          // wave 0..3
    const int lane = t & 63;
    const int cy   = lane >> 3, cx = lane & 7;   // pooled cell
    const int cy4  = cy << 2,  cx4 = cx << 2;

    float acc[2][4][16];
    #pragma unroll
    for (int ps = 0; ps < 2; ++ps)
        #pragma unroll
        for (int j = 0; j < 4; ++j)
            #pragma unroll
            for (int v = 0; v < 16; ++v) acc[ps][j][v] = 0.f;

    for (int p = 0; p < 4; ++p) {
        // ---- conv1 phase: channels p*8 .. p*8+7 -> c1t slots 0..7 ----
        {
            const int chb = p * 8 + wv * 2;   // each wave: 2 channels
            float w1r[2][27];
            #pragma unroll
            for (int j = 0; j < 2; ++j)
                #pragma unroll
                for (int q = 0; q < 27; ++q)
                    w1r[j][q] = w1[(chb + j) * 27 + q];
            const float bb0 = b1[chb], bb1 = b1[chb + 1];

            for (int it = 0; it < 10; ++it) {
                const int s = lane + it * 64;
                if (s < 578) {                       // 34 rows x 17 strips(2 cols)
                    const int y  = s / 17;
                    const int x0 = (s - y * 17) * 2;
                    float a00 = 0.f, a01 = 0.f, a10 = 0.f, a11 = 0.f;
                    #pragma unroll
                    for (int ci = 0; ci < 3; ++ci)
                        #pragma unroll
                        for (int dy = 0; dy < 3; ++dy) {
                            const float* rp = &simg[ci * 1296 + (y + dy) * 36 + x0];
                            const float i0 = rp[0], i1 = rp[1], i2 = rp[2], i3 = rp[3];
                            const int wb = ci * 9 + dy * 3;
                            const float w00 = w1r[0][wb], w01 = w1r[0][wb + 1], w02 = w1r[0][wb + 2];
                            const float w10 = w1r[1][wb], w11 = w1r[1][wb + 1], w12 = w1r[1][wb + 2];
                            a00 = fmaf(w00, i0, a00); a00 = fmaf(w01, i1, a00); a00 = fmaf(w02, i2, a00);
                            a01 = fmaf(w00, i1, a01); a01 = fmaf(w01, i2, a01); a01 = fmaf(w02, i3, a01);
                            a10 = fmaf(w10, i0, a10); a10 = fmaf(w11, i1, a10); a10 = fmaf(w12, i2, a10);
                            a11 = fmaf(w10, i1, a11); a11 = fmaf(w11, i2, a11); a11 = fmaf(w12, i3, a11);
                        }
                    const int gy  = oy - 1 + y;
                    const int gxg = ox - 1 + x0;
                    const bool iny  = (unsigned)gy < 128u;
                    const bool inx0 = iny && ((unsigned)gxg < 128u);
                    const bool inx1 = iny && ((unsigned)(gxg + 1) < 128u);
                    const int base = y * 34 + (y >> 2) + x0;
                    c1t[(wv * 2 + 0) * 1164 + base]     = inx0 ? fmaxf(a00 + bb0, 0.f) : 0.f;
                    c1t[(wv * 2 + 0) * 1164 + base + 1] = inx1 ? fmaxf(a01 + bb0, 0.f) : 0.f;
                    c1t[(wv * 2 + 1) * 1164 + base]     = inx0 ? fmaxf(a10 + bb1, 0.f) : 0.f;
                    c1t[(wv * 2 + 1) * 1164 + base + 1] = inx1 ? fmaxf(a11 + bb1, 0.f) : 0.f;
                }
            }
        }
        __syncthreads();

        // ---- conv2 accumulate over the 8 staged ci ----
        #pragma unroll 1
        for (int s = 0; s < 8; ++s) {
            const int ci = p * 8 + s;
            float win[6][6];
            #pragma unroll
            for (int r = 0; r < 6; ++r) {
                const int yy = cy4 + r;
                const float* rp = &c1t[s * 1164 + yy * 34 + (yy >> 2) + cx4];
                #pragma unroll
                for (int c = 0; c < 6; ++c) win[r][c] = rp[c];
            }
            #pragma unroll
            for (int ps = 0; ps < 2; ++ps) {
                #pragma unroll
                for (int j = 0; j < 4; ++j) {
                    const int oc = (wv + 4 * ps) * 4 + j;
                    const float* wp = &w2[(oc * 32 + ci) * 9];
                    const float q0 = wp[0], q1 = wp[1], q2 = wp[2],
                                q3 = wp[3], q4 = wp[4], q5 = wp[5],
                                q6 = wp[6], q7 = wp[7], q8 = wp[8];
                    #pragma unroll
                    for (int r2 = 0; r2 < 4; ++r2)
                        #pragma unroll
                        for (int c2 = 0; c2 < 4; ++c2) {
                            float sum = acc[ps][j][r2 * 4 + c2];
                            sum = fmaf(q0, win[r2][c2],     sum);
                            sum = fmaf(q1, win[r2][c2 + 1], sum);
                            sum = fmaf(q2, win[r2][c2 + 2], sum);
                            sum = fmaf(q3, win[r2 + 1][c2],     sum);
                            sum = fmaf(q4, win[r2 + 1][c2 + 1], sum);
                            sum = fmaf(q5, win[r2 + 1][c2 + 2], sum);
                            sum = fmaf(q6, win[r2 + 2][c2],     sum);
                            sum = fmaf(q7, win[r2 + 2][c2 + 1], sum);
                            sum = fmaf(q8, win[r2 + 2][c2 + 2], sum);
                            acc[ps][j][r2 * 4 + c2] = sum;
                        }
                }
            }
        }
        __syncthreads();
    }

    // epilogue: bias + relu + maxpool 4x4 (monotone: max first, then bias+relu)
    #pragma unroll
    for (int ps = 0; ps < 2; ++ps)
        #pragma unroll
        for (int j = 0; j < 4; ++j) {
            const int oc = (wv + 4 * ps) * 4 + j;
            float mx = acc[ps][j][0];
            #pragma unroll
            for (int v = 1; v < 16; ++v) mx = fmaxf(mx, acc[ps][j][v]);
            mx = fmaxf(mx + b2[oc], 0.f);
            P1[((b * 32 + oc) * 32 + (ty * 8 + cy)) * 32 + (tx * 8 + cx)] = mx;
        }
}

// ---------------------------------------------------------------------------
// Generic direct conv3x3 (+relu, optional 2x2 maxpool) for conv3..conv6.
// Input [B][CIN][HW][HW], weights [COUT][CIN][3][3], out [B][COUT][HW/POOL][HW/POOL].
// Block: region 16 x TW; ci staged 32 at a time into swizzled LDS tile.
// ---------------------------------------------------------------------------
template<int CIN, int COUT, int HW, int TW, int POOL>
__global__ __launch_bounds__(256, 3)
void k_conv(const float* __restrict__ in, const float* __restrict__ w,
            const float* __restrict__ bias, float* __restrict__ out)
{
    constexpr int SROW = TW + 2;
    constexpr int CS   = 18 * SROW + 8;            // swizzled ci stride
    constexpr int NPH  = CIN / 32;
    constexpr int NPASS = COUT / 16;
    constexpr int V    = (16 * TW) / 64;           // vals per cell: 4 or 2
    constexpr int CH   = (V == 4) ? 2 : 1;
    constexpr int CW   = 2;
    constexpr int NCX  = TW / CW;
    constexpr int WR   = CH + 2, WC = CW + 2;
    constexpr int TX   = HW / TW;

    __shared__ float tile[32 * CS];

    const int t    = threadIdx.x;
    const int wv   = t >> 6, lane = t & 63;
    const int cy   = lane / NCX, cx = lane - cy * NCX;
    const int nt   = blockIdx.x;
    const int b    = blockIdx.y;
    const int ry   = nt / TX, rx = nt - ry * TX;
    const int gy0  = ry * 16, gx0 = rx * TW;

    float acc[NPASS][4][V];
    #pragma unroll
    for (int ps = 0; ps < NPASS; ++ps)
        #pragma unroll
        for (int j = 0; j < 4; ++j)
            #pragma unroll
            for (int v = 0; v < V; ++v) acc[ps][j][v] = 0.f;

    for (int ph = 0; ph < NPH; ++ph) {
        if (ph) __syncthreads();
        for (int i = t; i < 32 * 18 * SROW; i += 256) {
            const int s = i / (18 * SROW), r = i - s * (18 * SROW);
            const int yy = r / SROW, xx = r - yy * SROW;
            const int gy = gy0 - 1 + yy, gx = gx0 - 1 + xx;
            float v = 0.f;
            if ((unsigned)gy < (unsigned)HW && (unsigned)gx < (unsigned)HW)
                v = in[((b * CIN + ph * 32 + s) * HW + gy) * HW + gx];
            tile[s * CS + yy * SROW + (yy >> 1) + xx] = v;
        }
        __syncthreads();

        #pragma unroll 1
        for (int s = 0; s < 32; ++s) {
            const int cig = ph * 32 + s;
            float win[WR][WC];
            #pragma unroll
            for (int r = 0; r < WR; ++r) {
                const int yy = cy * CH + r;
                const float* rp = &tile[s * CS + yy * SROW + (yy >> 1) + cx * CW];
                #pragma unroll
                for (int c = 0; c < WC; ++c) win[r][c] = rp[c];
            }
            #pragma unroll
            for (int ps = 0; ps < NPASS; ++ps) {
                #pragma unroll
                for (int j = 0; j < 4; ++j) {
                    const int oc = (ps * 4 + wv) * 4 + j;
                    const float* wp = &w[(oc * CIN + cig) * 9];
                    const float q0 = wp[0], q1 = wp[1], q2 = wp[2],
                                q3 = wp[3], q4 = wp[4], q5 = wp[5],
                                q6 = wp[6], q7 = wp[7], q8 = wp[8];
                    #pragma unroll
                    for (int r2 = 0; r2 < CH; ++r2)
                        #pragma unroll
                        for (int c2 = 0; c2 < CW; ++c2) {
                            float sum = acc[ps][j][r2 * CW + c2];
                            sum = fmaf(q0, win[r2][c2],     sum);
                            sum = fmaf(q1, win[r2][c2 + 1], sum);
                            sum = fmaf(q2, win[r2][c2 + 2], sum);
                            sum = fmaf(q3, win[r2 + 1][c2],     sum);
                            sum = fmaf(q4, win[r2 + 1][c2 + 1], sum);
                            sum = fmaf(q5, win[r2 + 1][c2 + 2], sum);
                            sum = fmaf(q6, win[r2 + 2][c2],     sum);
                            sum = fmaf(q7, win[r2 + 2][c2 + 1], sum);
                            sum = fmaf(q8, win[r2 + 2][c2 + 2], sum);
                            acc[ps][j][r2 * CW + c2] = sum;
                        }
                }
            }
        }
    }

    #pragma unroll
    for (int ps = 0; ps < NPASS; ++ps)
        #pragma unroll
        for (int j = 0; j < 4; ++j) {
            const int oc = (ps * 4 + wv) * 4 + j;
            const float bv = bias[oc];
            if constexpr (POOL == 2) {
                float mx = acc[ps][j][0];
                mx = fmaxf(mx, acc[ps][j][1]);
                mx = fmaxf(mx, acc[ps][j][2]);
                mx = fmaxf(mx, acc[ps][j][3]);
                mx = fmaxf(mx + bv, 0.f);
                out[((b * COUT + oc) * (HW / 2) + (gy0 >> 1) + cy) * (HW / 2) + (gx0 >> 1) + cx] = mx;
            } else {
                #pragma unroll
                for (int r2 = 0; r2 < CH; ++r2)
                    #pragma unroll
                    for (int c2 = 0; c2 < CW; ++c2)
                        out[((b * COUT + oc) * HW + gy0 + cy * CH + r2) * HW + gx0 + cx * CW + c2]
                            = fmaxf(acc[ps][j][r2 * CW + c2] + bv, 0.f);
            }
        }
}

// ---------------------------------------------------------------------------
// Split-K FC partial: A[128 x K] (row stride LDA) @ B[K x 512] -> part[by][128][512]
// grid (4 n-tiles of 128, K/KCHUNK). 8x8 register tile per thread.
// ---------------------------------------------------------------------------
template<int LDA, int KCHUNK>
__global__ __launch_bounds__(256, 2)
void k_fc_partial(const float* __restrict__ A, const float* __restrict__ Bw,
                  float* __restrict__ part)
{
    constexpr int S = 140;
    __shared__ float As[32 * S];
    __shared__ float Bs[32 * S];
    const int t  = threadIdx.x;
    const int tm = t >> 4, tn = t & 15;
    const int n0 = blockIdx.x * 128;
    const int k0 = blockIdx.y * KCHUNK;

    float acc[8][8];
    #pragma unroll
    for (int r = 0; r < 8; ++r)
        #pragma unroll
        for (int c = 0; c < 8; ++c) acc[r][c] = 0.f;

    for (int ks = 0; ks < KCHUNK / 32; ++ks) {
        if (ks) __syncthreads();
        const int kb = k0 + ks * 32;
        for (int i = t; i < 4096; i += 256) {           // A: [128m][32k] -> As[k][m']
            const int m = i >> 5, kk = i & 31;
            As[kk * S + m + ((m >> 5) << 2)] = A[m * LDA + kb + kk];
        }
        for (int i = t; i < 4096; i += 256) {           // B: [32k][128n]
            const int kk = i >> 7, n = i & 127;
            Bs[kk * S + n + ((n >> 5) << 2)] = Bw[(kb + kk) * 512 + n0 + n];
        }
        __syncthreads();
        #pragma unroll 2
        for (int kk = 0; kk < 32; ++kk) {
            const float* ap = &As[kk * S + tm * 8 + ((tm >> 2) << 2)];
            const float* bp = &Bs[kk * S + tn * 8 + ((tn >> 2) << 2)];
            float a[8], bb[8];
            #pragma unroll
            for (int q = 0; q < 8; ++q) { a[q] = ap[q]; bb[q] = bp[q]; }
            #pragma unroll
            for (int r = 0; r < 8; ++r)
                #pragma unroll
                for (int c = 0; c < 8; ++c)
                    acc[r][c] = fmaf(a[r], bb[c], acc[r][c]);
        }
    }

    const long pb = (long)blockIdx.y * 65536;
    #pragma unroll
    for (int r = 0; r < 8; ++r)
        #pragma unroll
        for (int c = 0; c < 8; ++c)
            part[pb + (tm * 8 + r) * 512 + n0 + tn * 8 + c] = acc[r][c];
}

// Deterministic split-K reduce + bias + relu. 65536 outputs, grid 64 x 256.
template<int NS>
__global__ __launch_bounds__(256)
void k_fc_reduce(const float* __restrict__ part, const float* __restrict__ bias,
                 float* __restrict__ H)
{
    const int f = (blockIdx.x * 256 + threadIdx.x) * 4;
    const int m = f >> 9, n = f & 511;
    float s0 = 0.f, s1 = 0.f, s2 = 0.f, s3 = 0.f;
    #pragma unroll 4
    for (int q = 0; q < NS; ++q) {
        const float* p = &part[(q * 128 + m) * 512 + n];
        s0 += p[0]; s1 += p[1]; s2 += p[2]; s3 += p[3];
    }
    H[f]     = fmaxf(s0 + bias[n],     0.f);
    H[f + 1] = fmaxf(s1 + bias[n + 1], 0.f);
    H[f + 2] = fmaxf(s2 + bias[n + 2], 0.f);
    H[f + 3] = fmaxf(s3 + bias[n + 3], 0.f);
}

// ---------------------------------------------------------------------------
// Final: FC3 + sampling (softplus/sigmoid/round-half-even) + patch gather.
// grid = 128 (batch), 256 threads.
// ---------------------------------------------------------------------------
__device__ __forceinline__ float softplusf(float x) {
    return (x > 20.f) ? x : log1pf(expf(x));
}
__device__ __forceinline__ float sigmoidf_(float x) {
    return 1.f / (1.f + expf(-x));
}

__global__ __launch_bounds__(256)
void k_final(const float* __restrict__ H2, const float* __restrict__ wl3,
             const float* __restrict__ bl3, const float* __restrict__ noise,
             const float* __restrict__ img, float* __restrict__ outp)
{
    __shared__ float h2[512];
    __shared__ float red[144];
    __shared__ float prep[36];
    __shared__ int ptsh[12], ptsw[12];
    const int b = blockIdx.x, t = threadIdx.x;

    h2[t]       = H2[b * 512 + t];
    h2[t + 256] = H2[b * 512 + 256 + t];
    __syncthreads();

    if (t < 144) {
        const int n = t >> 2, q = t & 3;
        float s = 0.f;
        for (int k = q * 128; k < q * 128 + 128; ++k)
            s = fmaf(h2[k], wl3[k * 36 + n], s);
        red[t] = s;
    }
    __syncthreads();
    if (t < 36)
        prep[t] = red[t * 4] + red[t * 4 + 1] + red[t * 4 + 2] + red[t * 4 + 3] + bl3[t];
    __syncthreads();

    if (t < 12) {
        const float m0 = prep[t * 3], m1 = prep[t * 3 + 1], sv = prep[t * 3 + 2];
        const float sig = softplusf(sv + 2.0f) * 128.f + 1e-7f;
        const float n0 = noise[(b * 12 + t) * 2], n1 = noise[(b * 12 + t) * 2 + 1];
        const float sa0 = m0 + sig * n0;
        const float sa1 = m1 + sig * n1;
        int p0 = (int)rintf(sigmoidf_(sa0) * 111.f);   // round half-to-even, = jnp.round
        int p1 = (int)rintf(sigmoidf_(sa1) * 111.f);
        p0 = min(max(p0, 0), 111);
        p1 = min(max(p1, 0), 111);
        const int RM = 1179648;                        // 128*12*3*256
        outp[RM        + (b * 12 + t) * 2 + 0] = m0;
        outp[RM        + (b * 12 + t) * 2 + 1] = m1;
        outp[RM + 3072 + (b * 12 + t) * 2 + 0] = sig;
        outp[RM + 3072 + (b * 12 + t) * 2 + 1] = sig;
        outp[RM + 6144 + (b * 12 + t) * 2 + 0] = sa0;
        outp[RM + 6144 + (b * 12 + t) * 2 + 1] = sa1;
        ptsh[t] = p0;
        ptsw[t] = p1;
    }
    __syncthreads();

    for (int i = t; i < 9216; i += 256) {              // [12][3][16][16]
        const int g  = i / 768, r = i - g * 768;
        const int c  = r >> 8, r2 = r & 255;
        const int y  = r2 >> 4, x = r2 & 15;
        outp[b * 9216 + i] = img[((b * 3 + c) * 128 + ptsh[g] + y) * 128 + (ptsw[g] + x)];
    }
}

// ---------------------------------------------------------------------------
extern "C" void kernel_launch(void* const* d_in, const int* in_sizes, int n_in,
                              void* d_out, int out_size, void* d_ws, size_t ws_size,
                              hipStream_t stream)
{
    const float* img  = (const float*)d_in[0];
    const float* nois = (const float*)d_in[1];
    const float* w1 = (const float*)d_in[2];  const float* b1 = (const float*)d_in[3];
    const float* w2 = (const float*)d_in[4];  const float* b2 = (const float*)d_in[5];
    const float* w3 = (const float*)d_in[6];  const float* b3 = (const float*)d_in[7];
    const float* w4 = (const float*)d_in[8];  const float* b4 = (const float*)d_in[9];
    const float* w5 = (const float*)d_in[10]; const float* b5 = (const float*)d_in[11];
    const float* w6 = (const float*)d_in[12]; const float* b6 = (const float*)d_in[13];
    const float* wl1 = (const float*)d_in[14]; const float* bl1 = (const float*)d_in[15];
    const float* wl2 = (const float*)d_in[16]; const float* bl2 = (const float*)d_in[17];
    const float* wl3 = (const float*)d_in[18]; const float* bl3 = (const float*)d_in[19];
    float* out = (float*)d_out;
    float* ws  = (float*)d_ws;

    // workspace layout (floats)
    float* P1  = ws;                  // [128][32][32][32]   4,194,304
    float* A3  = ws + 4194304;        // [128][64][32][32]   8,388,608
    float* P2  = ws + 12582912;       // [128][64][16][16]   2,097,152
    float* A5  = ws + 14680064;       // [128][128][16][16]  4,194,304
    float* A6  = ws + 18874368;       // [128][128][16][16]  4,194,304
    float* FP1 = ws + 23068672;       // [64][128][512]      4,194,304
    float* H1  = ws + 27262976;       // [128][512]             65,536
    float* FP2 = ws + 27328512;       // [8][128][512]         524,288
    float* H2  = ws + 27852800;       // [128][512]             65,536
    // total 27,918,336 floats = ~111.7 MB

    hipLaunchKernelGGL(k_conv12, dim3(16, 128), dim3(256), 0, stream,
                       img, w1, b1, w2, b2, P1);
    hipLaunchKernelGGL((k_conv<32, 64, 32, 16, 1>), dim3(4, 128), dim3(256), 0, stream,
                       P1, w3, b3, A3);
    hipLaunchKernelGGL((k_conv<64, 64, 32, 16, 2>), dim3(4, 128), dim3(256), 0, stream,
                       A3, w4, b4, P2);
    hipLaunchKernelGGL((k_conv<64, 128, 16, 8, 1>), dim3(2, 128), dim3(256), 0, stream,
                       P2, w5, b5, A5);
    hipLaunchKernelGGL((k_conv<128, 128, 16, 8, 1>), dim3(2, 128), dim3(256), 0, stream,
                       A5, w6, b6, A6);
    hipLaunchKernelGGL((k_fc_partial<32768, 512>), dim3(4, 64), dim3(256), 0, stream,
                       A6, wl1, FP1);
    hipLaunchKernelGGL((k_fc_reduce<64>), dim3(64), dim3(256), 0, stream,
                       FP1, bl1, H1);
    hipLaunchKernelGGL((k_fc_partial<512, 64>), dim3(4, 8), dim3(256), 0, stream,
                       H1, wl2, FP2);
    hipLaunchKernelGGL((k_fc_reduce<8>), dim3(64), dim3(256), 0, stream,
                       FP2, bl2, H2);
    hipLaunchKernelGGL(k_final, dim3(128), dim3(256), 0, stream,
                       H2, wl3, bl3, nois, img, out);
}

// Round 2
// 1189.579 us; speedup vs baseline: 2.0751x; 2.0751x over previous
//
#include <hip/hip_runtime.h>
#include <math.h>

// ---------------------------------------------------------------------------
// Kernel 1: fused conv1(3->32) + relu + conv2(32->32) + relu + maxpool4
// Output NOW IN NHWC: P1[b][y][x][oc], 32x32 spatial, 32 ch.
// ---------------------------------------------------------------------------
__global__ __launch_bounds__(256, 2)
void k_conv12(const float* __restrict__ img, const float* __restrict__ w1,
              const float* __restrict__ b1, const float* __restrict__ w2,
              const float* __restrict__ b2, float* __restrict__ P1)
{
    __shared__ float simg[3 * 36 * 36];
    __shared__ float c1t[8 * 1164];

    const int t  = threadIdx.x;
    const int bt = blockIdx.x;            // 0..15
    const int b  = blockIdx.y;
    const int ty = bt >> 2, tx = bt & 3;
    const int oy = ty * 32, ox = tx * 32;

    for (int i = t; i < 3 * 36 * 36; i += 256) {
        const int ci = i / 1296, r = i - ci * 1296;
        const int yy = r / 36, xx = r - yy * 36;
        const int gy = oy - 2 + yy, gx = ox - 2 + xx;
        float v = 0.f;
        if ((unsigned)gy < 128u && (unsigned)gx < 128u)
            v = img[((b * 3 + ci) * 128 + gy) * 128 + gx];
        simg[i] = v;
    }
    __syncthreads();

    const int wv   = t >> 6;
    const int lane = t & 63;
    const int cy   = lane >> 3, cx = lane & 7;
    const int cy4  = cy << 2,  cx4 = cx << 2;

    float acc[2][4][16];
    #pragma unroll
    for (int ps = 0; ps < 2; ++ps)
        #pragma unroll
        for (int j = 0; j < 4; ++j)
            #pragma unroll
            for (int v = 0; v < 16; ++v) acc[ps][j][v] = 0.f;

    for (int p = 0; p < 4; ++p) {
        {
            const int chb = p * 8 + wv * 2;
            float w1r[2][27];
            #pragma unroll
            for (int j = 0; j < 2; ++j)
                #pragma unroll
                for (int q = 0; q < 27; ++q)
                    w1r[j][q] = w1[(chb + j) * 27 + q];
            const float bb0 = b1[chb], bb1 = b1[chb + 1];

            for (int it = 0; it < 10; ++it) {
                const int s = lane + it * 64;
                if (s < 578) {
                    const int y  = s / 17;
                    const int x0 = (s - y * 17) * 2;
                    float a00 = 0.f, a01 = 0.f, a10 = 0.f, a11 = 0.f;
                    #pragma unroll
                    for (int ci = 0; ci < 3; ++ci)
                        #pragma unroll
                        for (int dy = 0; dy < 3; ++dy) {
                            const float* rp = &simg[ci * 1296 + (y + dy) * 36 + x0];
                            const float i0 = rp[0], i1 = rp[1], i2 = rp[2], i3 = rp[3];
                            const int wb = ci * 9 + dy * 3;
                            const float w00 = w1r[0][wb], w01 = w1r[0][wb + 1], w02 = w1r[0][wb + 2];
                            const float w10 = w1r[1][wb], w11 = w1r[1][wb + 1], w12 = w1r[1][wb + 2];
                            a00 = fmaf(w00, i0, a00); a00 = fmaf(w01, i1, a00); a00 = fmaf(w02, i2, a00);
                            a01 = fmaf(w00, i1, a01); a01 = fmaf(w01, i2, a01); a01 = fmaf(w02, i3, a01);
                            a10 = fmaf(w10, i0, a10); a10 = fmaf(w11, i1, a10); a10 = fmaf(w12, i2, a10);
                            a11 = fmaf(w10, i1, a11); a11 = fmaf(w11, i2, a11); a11 = fmaf(w12, i3, a11);
                        }
                    const int gy  = oy - 1 + y;
                    const int gxg = ox - 1 + x0;
                    const bool iny  = (unsigned)gy < 128u;
                    const bool inx0 = iny && ((unsigned)gxg < 128u);
                    const bool inx1 = iny && ((unsigned)(gxg + 1) < 128u);
                    const int base = y * 34 + (y >> 2) + x0;
                    c1t[(wv * 2 + 0) * 1164 + base]     = inx0 ? fmaxf(a00 + bb0, 0.f) : 0.f;
                    c1t[(wv * 2 + 0) * 1164 + base + 1] = inx1 ? fmaxf(a01 + bb0, 0.f) : 0.f;
                    c1t[(wv * 2 + 1) * 1164 + base]     = inx0 ? fmaxf(a10 + bb1, 0.f) : 0.f;
                    c1t[(wv * 2 + 1) * 1164 + base + 1] = inx1 ? fmaxf(a11 + bb1, 0.f) : 0.f;
                }
            }
        }
        __syncthreads();

        #pragma unroll 1
        for (int s = 0; s < 8; ++s) {
            const int ci = p * 8 + s;
            float win[6][6];
            #pragma unroll
            for (int r = 0; r < 6; ++r) {
                const int yy = cy4 + r;
                const float* rp = &c1t[s * 1164 + yy * 34 + (yy >> 2) + cx4];
                #pragma unroll
                for (int c = 0; c < 6; ++c) win[r][c] = rp[c];
            }
            #pragma unroll
            for (int ps = 0; ps < 2; ++ps) {
                #pragma unroll
                for (int j = 0; j < 4; ++j) {
                    const int oc = (wv + 4 * ps) * 4 + j;
                    const float* wp = &w2[(oc * 32 + ci) * 9];
                    const float q0 = wp[0], q1 = wp[1], q2 = wp[2],
                                q3 = wp[3], q4 = wp[4], q5 = wp[5],
                                q6 = wp[6], q7 = wp[7], q8 = wp[8];
                    #pragma unroll
                    for (int r2 = 0; r2 < 4; ++r2)
                        #pragma unroll
                        for (int c2 = 0; c2 < 4; ++c2) {
                            float sum = acc[ps][j][r2 * 4 + c2];
                            sum = fmaf(q0, win[r2][c2],     sum);
                            sum = fmaf(q1, win[r2][c2 + 1], sum);
                            sum = fmaf(q2, win[r2][c2 + 2], sum);
                            sum = fmaf(q3, win[r2 + 1][c2],     sum);
                            sum = fmaf(q4, win[r2 + 1][c2 + 1], sum);
                            sum = fmaf(q5, win[r2 + 1][c2 + 2], sum);
                            sum = fmaf(q6, win[r2 + 2][c2],     sum);
                            sum = fmaf(q7, win[r2 + 2][c2 + 1], sum);
                            sum = fmaf(q8, win[r2 + 2][c2 + 2], sum);
                            acc[ps][j][r2 * 4 + c2] = sum;
                        }
                }
            }
        }
        __syncthreads();
    }

    // epilogue: maxpool 4x4 then bias+relu; NHWC store, float4 over oc
    const int base = ((b * 1024) + (ty * 8 + cy) * 32 + (tx * 8 + cx)) * 32;
    #pragma unroll
    for (int ps = 0; ps < 2; ++ps) {
        float vals[4];
        #pragma unroll
        for (int j = 0; j < 4; ++j) {
            const int oc = (wv + 4 * ps) * 4 + j;
            float mx = acc[ps][j][0];
            #pragma unroll
            for (int v = 1; v < 16; ++v) mx = fmaxf(mx, acc[ps][j][v]);
            vals[j] = fmaxf(mx + b2[oc], 0.f);
        }
        float4 o = make_float4(vals[0], vals[1], vals[2], vals[3]);
        *(float4*)(&P1[base + (wv + 4 * ps) * 4]) = o;
    }
}

// ---------------------------------------------------------------------------
// Weight repack: OIHW -> [k=(tap*CIN+ci)][oc]   (coalesced GEMM B operand)
// ---------------------------------------------------------------------------
__global__ void k_wrepack(const float* __restrict__ w, float* __restrict__ Wk,
                          int CIN, int COUT)
{
    const int idx = blockIdx.x * 256 + threadIdx.x;
    if (idx >= CIN * COUT * 9) return;
    const int tap = idx / (CIN * COUT);
    const int rem = idx - tap * CIN * COUT;
    const int ci  = rem / COUT;
    const int oc  = rem - ci * COUT;
    Wk[idx] = w[(oc * CIN + ci) * 9 + tap];
}

// ---------------------------------------------------------------------------
// Implicit-GEMM conv3x3 (NHWC): out[m][oc] = sum_k A_im2col[m][k] * Wk[k][oc]
// m = (b,y,x); k = tap*CIN+ci (chunks of 32 stay within one tap).
// 16x16 thread grid, TM x TN register tile. bias+relu epilogue.
// ---------------------------------------------------------------------------
template<int CIN, int COUT, int HW, int BM, int TM, int TN>
__global__ __launch_bounds__(256, 4)
void k_cgemm(const float* __restrict__ in, const float* __restrict__ Bk,
             const float* __restrict__ bias, float* __restrict__ out)
{
    constexpr int BN = 16 * TN;
    static_assert(BN == COUT, "one n-tile");
    constexpr int SA = (BM == 128) ? 140 : 68;
    constexpr int SB = (BN == 128) ? 140 : 68;
    constexpr int LOG = (HW == 32) ? 5 : 4;
    constexpr int NCH = (CIN * 9) / 32;
    constexpr int AF4 = (BM * 8) / 256;        // float4 A-loads per thread
    constexpr int BF4 = (BN * 8) / 256;        // float4 B-loads per thread

    __shared__ __align__(16) float As[32 * SA];
    __shared__ __align__(16) float Bs[32 * SB];

    const int t  = threadIdx.x;
    const int tm = t >> 4, tn = t & 15;
    const int m0 = blockIdx.x * BM;

    float acc[TM][TN];
    #pragma unroll
    for (int r = 0; r < TM; ++r)
        #pragma unroll
        for (int c = 0; c < TN; ++c) acc[r][c] = 0.f;

    #pragma unroll 1
    for (int ch = 0; ch < NCH; ++ch) {
        if (ch) __syncthreads();
        const int kb  = ch * 32;
        const int tap = kb / CIN;
        const int c0  = kb - tap * CIN;
        const int dy  = tap / 3 - 1, dx = tap - (tap / 3) * 3 - 1;

        // A tile: BM rows x 32 ci (im2col with zero pad), transposed into LDS
        #pragma unroll
        for (int j = 0; j < AF4; ++j) {
            const int q    = t + 256 * j;
            const int mrow = q >> 3, c4 = q & 7;
            const int m    = m0 + mrow;
            const int yx   = m & (HW * HW - 1);
            const int b    = m >> (2 * LOG);
            const int y    = yx >> LOG, x = yx & (HW - 1);
            const int iy   = y + dy, ix = x + dx;
            float4 v = make_float4(0.f, 0.f, 0.f, 0.f);
            if ((unsigned)iy < (unsigned)HW && (unsigned)ix < (unsigned)HW)
                v = *(const float4*)(in + ((b * HW + iy) * HW + ix) * CIN + c0 + c4 * 4);
            const int ms = mrow + ((mrow >> 5) << 2);
            As[(c4 * 4 + 0) * SA + ms] = v.x;
            As[(c4 * 4 + 1) * SA + ms] = v.y;
            As[(c4 * 4 + 2) * SA + ms] = v.z;
            As[(c4 * 4 + 3) * SA + ms] = v.w;
        }
        // B tile: 32 k-rows x BN oc (coalesced from repacked Wk)
        #pragma unroll
        for (int j = 0; j < BF4; ++j) {
            const int q  = t + 256 * j;
            const int kk = q / (BN / 4), n4 = q - kk * (BN / 4);
            float4 v = *(const float4*)(Bk + (kb + kk) * COUT + n4 * 4);
            *(float4*)(&Bs[kk * SB + n4 * 4 + ((n4 >> 3) << 2)]) = v;
        }
        __syncthreads();

        #pragma unroll 2
        for (int kk = 0; kk < 32; ++kk) {
            const float* ap = &As[kk * SA + tm * TM + (((tm * TM) >> 5) << 2)];
            const float* bp = &Bs[kk * SB + tn * TN + (((tn * TN) >> 5) << 2)];
            float a[TM], bb[TN];
            #pragma unroll
            for (int j = 0; j < TM; j += 4) {
                const float4 v = *(const float4*)(ap + j);
                a[j] = v.x; a[j + 1] = v.y; a[j + 2] = v.z; a[j + 3] = v.w;
            }
            #pragma unroll
            for (int j = 0; j < TN; j += 4) {
                const float4 v = *(const float4*)(bp + j);
                bb[j] = v.x; bb[j + 1] = v.y; bb[j + 2] = v.z; bb[j + 3] = v.w;
            }
            #pragma unroll
            for (int r = 0; r < TM; ++r)
                #pragma unroll
                for (int c = 0; c < TN; ++c)
                    acc[r][c] = fmaf(a[r], bb[c], acc[r][c]);
        }
    }

    #pragma unroll
    for (int r = 0; r < TM; ++r) {
        const int m = m0 + tm * TM + r;
        float* op = out + m * COUT + tn * TN;
        #pragma unroll
        for (int c = 0; c < TN; c += 4) {
            float4 v;
            v.x = fmaxf(acc[r][c + 0] + bias[tn * TN + c + 0], 0.f);
            v.y = fmaxf(acc[r][c + 1] + bias[tn * TN + c + 1], 0.f);
            v.z = fmaxf(acc[r][c + 2] + bias[tn * TN + c + 2], 0.f);
            v.w = fmaxf(acc[r][c + 3] + bias[tn * TN + c + 3], 0.f);
            *(float4*)(op + c) = v;
        }
    }
}

// ---------------------------------------------------------------------------
// 2x2 maxpool, NHWC [128][32][32][64] -> [128][16][16][64]
// ---------------------------------------------------------------------------
__global__ __launch_bounds__(256)
void k_pool2(const float* __restrict__ in, float* __restrict__ out)
{
    const int g = blockIdx.x * 256 + threadIdx.x;   // 524288 float4 outputs
    const int c4 = g & 15, xo = (g >> 4) & 15, yo = (g >> 8) & 15, b = g >> 12;
    const float* p = in + ((b * 32 + yo * 2) * 32 + xo * 2) * 64 + c4 * 4;
    const float4 v0 = *(const float4*)(p);
    const float4 v1 = *(const float4*)(p + 64);
    const float4 v2 = *(const float4*)(p + 2048);
    const float4 v3 = *(const float4*)(p + 2112);
    float4 o;
    o.x = fmaxf(fmaxf(v0.x, v1.x), fmaxf(v2.x, v3.x));
    o.y = fmaxf(fmaxf(v0.y, v1.y), fmaxf(v2.y, v3.y));
    o.z = fmaxf(fmaxf(v0.z, v1.z), fmaxf(v2.z, v3.z));
    o.w = fmaxf(fmaxf(v0.w, v1.w), fmaxf(v2.w, v3.w));
    *(float4*)(out + g * 4) = o;
}

// ---------------------------------------------------------------------------
// Split-K FC partial: A[128 x K] @ B[K x 512] -> part[ky][128][512]
// TN=4 -> 64-wide n-tiles (more blocks). PERM remaps k for NHWC-flattened A.
// ---------------------------------------------------------------------------
template<int LDA, int KCHUNK, int TN, bool PERM>
__global__ __launch_bounds__(256, 2)
void k_fc_partial(const float* __restrict__ A, const float* __restrict__ Bw,
                  float* __restrict__ part)
{
    constexpr int BN = 16 * TN;
    constexpr int SA = 140;
    constexpr int SB = (BN == 128) ? 140 : 68;
    __shared__ __align__(16) float As[32 * SA];
    __shared__ __align__(16) float Bs[32 * SB];
    const int t  = threadIdx.x;
    const int tm = t >> 4, tn = t & 15;
    const int n0 = blockIdx.x * BN;
    const int k0 = blockIdx.y * KCHUNK;

    float acc[8][TN];
    #pragma unroll
    for (int r = 0; r < 8; ++r)
        #pragma unroll
        for (int c = 0; c < TN; ++c) acc[r][c] = 0.f;

    #pragma unroll 1
    for (int ks = 0; ks < KCHUNK / 32; ++ks) {
        if (ks) __syncthreads();
        const int kb = k0 + ks * 32;
        for (int i = t; i < 4096; i += 256) {
            const int m = i >> 5, kk = i & 31;
            As[kk * SA + m + ((m >> 5) << 2)] = A[m * LDA + kb + kk];
        }
        for (int i = t; i < 32 * BN; i += 256) {
            const int kk = i / BN, n = i - kk * BN;
            const int krow = kb + kk;
            const int kref = PERM ? ((krow & 127) * 256 + (krow >> 7)) : krow;
            Bs[kk * SB + n + ((n >> 5) << 2)] = Bw[kref * 512 + n0 + n];
        }
        __syncthreads();
        #pragma unroll 2
        for (int kk = 0; kk < 32; ++kk) {
            const float* ap = &As[kk * SA + tm * 8 + ((tm >> 2) << 2)];
            const float* bp = &Bs[kk * SB + tn * TN + (((tn * TN) >> 5) << 2)];
            float a[8], bb[TN];
            #pragma unroll
            for (int q = 0; q < 8; q += 4) {
                const float4 v = *(const float4*)(ap + q);
                a[q] = v.x; a[q + 1] = v.y; a[q + 2] = v.z; a[q + 3] = v.w;
            }
            #pragma unroll
            for (int q = 0; q < TN; q += 4) {
                const float4 v = *(const float4*)(bp + q);
                bb[q] = v.x; bb[q + 1] = v.y; bb[q + 2] = v.z; bb[q + 3] = v.w;
            }
            #pragma unroll
            for (int r = 0; r < 8; ++r)
                #pragma unroll
                for (int c = 0; c < TN; ++c)
                    acc[r][c] = fmaf(a[r], bb[c], acc[r][c]);
        }
    }

    const long pb = (long)blockIdx.y * 65536;
    #pragma unroll
    for (int r = 0; r < 8; ++r)
        #pragma unroll
        for (int c = 0; c < TN; ++c)
            part[pb + (tm * 8 + r) * 512 + n0 + tn * TN + c] = acc[r][c];
}

template<int NS>
__global__ __launch_bounds__(256)
void k_fc_reduce(const float* __restrict__ part, const float* __restrict__ bias,
                 float* __restrict__ H)
{
    const int f = (blockIdx.x * 256 + threadIdx.x) * 4;
    const int m = f >> 9, n = f & 511;
    float s0 = 0.f, s1 = 0.f, s2 = 0.f, s3 = 0.f;
    #pragma unroll 4
    for (int q = 0; q < NS; ++q) {
        const float* p = &part[(q * 128 + m) * 512 + n];
        s0 += p[0]; s1 += p[1]; s2 += p[2]; s3 += p[3];
    }
    H[f]     = fmaxf(s0 + bias[n],     0.f);
    H[f + 1] = fmaxf(s1 + bias[n + 1], 0.f);
    H[f + 2] = fmaxf(s2 + bias[n + 2], 0.f);
    H[f + 3] = fmaxf(s3 + bias[n + 3], 0.f);
}

// ---------------------------------------------------------------------------
// Final: FC3 + sampling + patch gather
// ---------------------------------------------------------------------------
__device__ __forceinline__ float softplusf(float x) {
    return (x > 20.f) ? x : log1pf(expf(x));
}
__device__ __forceinline__ float sigmoidf_(float x) {
    return 1.f / (1.f + expf(-x));
}

__global__ __launch_bounds__(256)
void k_final(const float* __restrict__ H2, const float* __restrict__ wl3,
             const float* __restrict__ bl3, const float* __restrict__ noise,
             const float* __restrict__ img, float* __restrict__ outp)
{
    __shared__ float h2[512];
    __shared__ float red[144];
    __shared__ float prep[36];
    __shared__ int ptsh[12], ptsw[12];
    const int b = blockIdx.x, t = threadIdx.x;

    h2[t]       = H2[b * 512 + t];
    h2[t + 256] = H2[b * 512 + 256 + t];
    __syncthreads();

    if (t < 144) {
        const int n = t >> 2, q = t & 3;
        float s = 0.f;
        for (int k = q * 128; k < q * 128 + 128; ++k)
            s = fmaf(h2[k], wl3[k * 36 + n], s);
        red[t] = s;
    }
    __syncthreads();
    if (t < 36)
        prep[t] = red[t * 4] + red[t * 4 + 1] + red[t * 4 + 2] + red[t * 4 + 3] + bl3[t];
    __syncthreads();

    if (t < 12) {
        const float m0 = prep[t * 3], m1 = prep[t * 3 + 1], sv = prep[t * 3 + 2];
        const float sig = softplusf(sv + 2.0f) * 128.f + 1e-7f;
        const float n0 = noise[(b * 12 + t) * 2], n1 = noise[(b * 12 + t) * 2 + 1];
        const float sa0 = m0 + sig * n0;
        const float sa1 = m1 + sig * n1;
        int p0 = (int)rintf(sigmoidf_(sa0) * 111.f);
        int p1 = (int)rintf(sigmoidf_(sa1) * 111.f);
        p0 = min(max(p0, 0), 111);
        p1 = min(max(p1, 0), 111);
        const int RM = 1179648;
        outp[RM        + (b * 12 + t) * 2 + 0] = m0;
        outp[RM        + (b * 12 + t) * 2 + 1] = m1;
        outp[RM + 3072 + (b * 12 + t) * 2 + 0] = sig;
        outp[RM + 3072 + (b * 12 + t) * 2 + 1] = sig;
        outp[RM + 6144 + (b * 12 + t) * 2 + 0] = sa0;
        outp[RM + 6144 + (b * 12 + t) * 2 + 1] = sa1;
        ptsh[t] = p0;
        ptsw[t] = p1;
    }
    __syncthreads();

    for (int i = t; i < 9216; i += 256) {
        const int g  = i / 768, r = i - g * 768;
        const int c  = r >> 8, r2 = r & 255;
        const int y  = r2 >> 4, x = r2 & 15;
        outp[b * 9216 + i] = img[((b * 3 + c) * 128 + ptsh[g] + y) * 128 + (ptsw[g] + x)];
    }
}

// ---------------------------------------------------------------------------
extern "C" void kernel_launch(void* const* d_in, const int* in_sizes, int n_in,
                              void* d_out, int out_size, void* d_ws, size_t ws_size,
                              hipStream_t stream)
{
    const float* img  = (const float*)d_in[0];
    const float* nois = (const float*)d_in[1];
    const float* w1 = (const float*)d_in[2];  const float* b1 = (const float*)d_in[3];
    const float* w2 = (const float*)d_in[4];  const float* b2 = (const float*)d_in[5];
    const float* w3 = (const float*)d_in[6];  const float* b3 = (const float*)d_in[7];
    const float* w4 = (const float*)d_in[8];  const float* b4 = (const float*)d_in[9];
    const float* w5 = (const float*)d_in[10]; const float* b5 = (const float*)d_in[11];
    const float* w6 = (const float*)d_in[12]; const float* b6 = (const float*)d_in[13];
    const float* wl1 = (const float*)d_in[14]; const float* bl1 = (const float*)d_in[15];
    const float* wl2 = (const float*)d_in[16]; const float* bl2 = (const float*)d_in[17];
    const float* wl3 = (const float*)d_in[18]; const float* bl3 = (const float*)d_in[19];
    float* out = (float*)d_out;
    float* ws  = (float*)d_ws;

    // workspace layout (floats), total 26,621,952 fl = 106.5 MB
    float* P1   = ws;                    // [128][32][32][32] NHWC  4,194,304 (R1)
    float* P2   = ws;                    // [128][16][16][64] NHWC  2,097,152 (aliases P1, P1 dead)
    float* A3   = ws + 4194304;          // [128][32][32][64] NHWC  8,388,608
    float* A4f  = ws + 12582912;         // [128][32][32][64] NHWC  8,388,608 (R3)
    float* A5   = ws + 12582912;         // [128][16][16][128] NHWC 4,194,304 (aliases A4f, dead)
    float* A6   = ws + 16777216;         // [128][16][16][128] NHWC 4,194,304
    float* FP1  = ws + 20971520;         // [64][128][512]          4,194,304
    float* H1   = ws + 25165824;         // [128][512]                 65,536
    float* FP2  = ws + 25231360;         // [16][128][512]          1,048,576
    float* H2   = ws + 26279936;         // [128][512]                 65,536
    float* Wk3  = ws + 26345472;         // [288][64]                  18,432
    float* Wk4  = ws + 26363904;         // [576][64]                  36,864
    float* Wk5  = ws + 26400768;         // [576][128]                 73,728
    float* Wk6  = ws + 26474496;         // [1152][128]               147,456

    // weight repacks (tiny)
    hipLaunchKernelGGL(k_wrepack, dim3(72),  dim3(256), 0, stream, w3, Wk3, 32, 64);
    hipLaunchKernelGGL(k_wrepack, dim3(144), dim3(256), 0, stream, w4, Wk4, 64, 64);
    hipLaunchKernelGGL(k_wrepack, dim3(288), dim3(256), 0, stream, w5, Wk5, 64, 128);
    hipLaunchKernelGGL(k_wrepack, dim3(576), dim3(256), 0, stream, w6, Wk6, 128, 128);

    hipLaunchKernelGGL(k_conv12, dim3(16, 128), dim3(256), 0, stream,
                       img, w1, b1, w2, b2, P1);
    // conv3: M=131072 N=64 K=288, 128x64 tiles, grid 1024
    hipLaunchKernelGGL((k_cgemm<32, 64, 32, 128, 8, 4>), dim3(1024), dim3(256), 0, stream,
                       P1, Wk3, b3, A3);
    // conv4: M=131072 N=64 K=576, grid 1024 (relu'd full-res out, pool next)
    hipLaunchKernelGGL((k_cgemm<64, 64, 32, 128, 8, 4>), dim3(1024), dim3(256), 0, stream,
                       A3, Wk4, b4, A4f);
    hipLaunchKernelGGL(k_pool2, dim3(2048), dim3(256), 0, stream, A4f, P2);
    // conv5: M=32768 N=128 K=576, 64x128 tiles, grid 512
    hipLaunchKernelGGL((k_cgemm<64, 128, 16, 64, 4, 8>), dim3(512), dim3(256), 0, stream,
                       P2, Wk5, b5, A5);
    // conv6: M=32768 N=128 K=1152, grid 512
    hipLaunchKernelGGL((k_cgemm<128, 128, 16, 64, 4, 8>), dim3(512), dim3(256), 0, stream,
                       A5, Wk6, b6, A6);
    // FC1: K=32768 (NHWC-permuted), 64-wide n-tiles -> grid (8,64)=512 blocks
    hipLaunchKernelGGL((k_fc_partial<32768, 512, 4, true>), dim3(8, 64), dim3(256), 0, stream,
                       A6, wl1, FP1);
    hipLaunchKernelGGL(k_fc_reduce<64>, dim3(64), dim3(256), 0, stream, FP1, bl1, H1);
    // FC2: K=512, 16 k-slices of 32 -> grid (8,16)=128 blocks
    hipLaunchKernelGGL((k_fc_partial<512, 32, 4, false>), dim3(8, 16), dim3(256), 0, stream,
                       H1, wl2, FP2);
    hipLaunchKernelGGL(k_fc_reduce<16>, dim3(64), dim3(256), 0, stream, FP2, bl2, H2);
    hipLaunchKernelGGL(k_final, dim3(128), dim3(256), 0, stream,
                       H2, wl3, bl3, nois, img, out);
}

// Round 3
// 1081.601 us; speedup vs baseline: 2.2823x; 1.0998x over previous
//
#include <hip/hip_runtime.h>
#include <math.h>

// ---------------------------------------------------------------------------
// Kernel 1: fused conv1(3->32) + relu + conv2(32->32) + relu + maxpool4
// Output NHWC: P1[b][py][px][oc], 32x32 spatial, 32 ch.
// Tile: conv2 region 16 rows x 32 cols (grid 32 x 128). 4 blocks/CU target.
//  - conv1 tile c1t[8ch][18][36] (stride 36 = aligned rows, balanced banks)
//  - weights via readfirstlane-uniform scalar loads (s_load, no VMEM)
//  - thread = (wave=8 oc, lane=(pooled cell, half)): acc[8 oc][2x4 cells]
// ---------------------------------------------------------------------------
__global__ __launch_bounds__(256, 4)
void k_conv12(const float* __restrict__ img, const float* __restrict__ w1,
              const float* __restrict__ b1, const float* __restrict__ w2,
              const float* __restrict__ b2, float* __restrict__ P1)
{
    __shared__ float simg[3 * 20 * 36 + 8];   // 2168 fl = 8.7 KB
    __shared__ float c1t[8 * 18 * 36];        // 5184 fl = 20.7 KB

    const int t  = threadIdx.x;
    const int bt = blockIdx.x;            // 0..31
    const int b  = blockIdx.y;
    const int ty = bt >> 2, tx = bt & 3;  // ty: 8 row-tiles of 16, tx: 4 col-tiles of 32
    const int oy = ty * 16, ox = tx * 32;

    // stage image tile [3][20][36], origin (oy-2, ox-2), zero-padded
    for (int i = t; i < 2160; i += 256) {
        const int ci = i / 720, r = i - ci * 720;
        const int yy = r / 36, xx = r - yy * 36;
        const int gy = oy - 2 + yy, gx = ox - 2 + xx;
        float v = 0.f;
        if ((unsigned)gy < 128u && (unsigned)gx < 128u)
            v = img[((b * 3 + ci) * 128 + gy) * 128 + gx];
        simg[i] = v;
    }

    const int wvu  = __builtin_amdgcn_readfirstlane(t >> 6);  // wave id, uniform
    const int lane = t & 63;
    const int cell = lane >> 1, half = lane & 1;
    const int cy   = cell >> 3, cx = cell & 7;    // pooled cell (4 x 8 grid)
    const int ry0  = cy * 4 + half * 2;           // conv2 out row base (2 rows)
    const int cx4  = cx * 4;                      // conv2 out col base (4 cols)

    float acc[8][8];
    #pragma unroll
    for (int j = 0; j < 8; ++j)
        #pragma unroll
        for (int v = 0; v < 8; ++v) acc[j][v] = 0.f;

    for (int p = 0; p < 4; ++p) {
        __syncthreads();   // simg ready (p=0) / prev conv2 reads done (p>0)

        // ---- conv1: this wave computes channels chb, chb+1 over 162 strips ----
        {
            const int chb = p * 8 + wvu * 2;      // uniform -> s_load weights
            float w1r[2][27];
            #pragma unroll
            for (int j = 0; j < 2; ++j)
                #pragma unroll
                for (int q = 0; q < 27; ++q)
                    w1r[j][q] = w1[(chb + j) * 27 + q];
            const float bb0 = b1[chb], bb1 = b1[chb + 1];

            #pragma unroll 1
            for (int it = 0; it < 3; ++it) {
                const int s = lane + it * 64;
                if (s < 162) {                    // 18 rows x 9 strips of 4 cols
                    const int y  = s / 9;
                    const int x0 = (s - y * 9) * 4;
                    float a0[4] = {0.f, 0.f, 0.f, 0.f};
                    float a1[4] = {0.f, 0.f, 0.f, 0.f};
                    #pragma unroll
                    for (int ci = 0; ci < 3; ++ci)
                        #pragma unroll
                        for (int dy = 0; dy < 3; ++dy) {
                            const float* rp = &simg[ci * 720 + (y + dy) * 36 + x0];
                            const float4 v4 = *(const float4*)rp;
                            const float2 v2 = *(const float2*)(rp + 4);
                            const float in6[6] = {v4.x, v4.y, v4.z, v4.w, v2.x, v2.y};
                            const int wb = ci * 9 + dy * 3;
                            #pragma unroll
                            for (int c = 0; c < 4; ++c) {
                                a0[c] = fmaf(w1r[0][wb],     in6[c],     a0[c]);
                                a0[c] = fmaf(w1r[0][wb + 1], in6[c + 1], a0[c]);
                                a0[c] = fmaf(w1r[0][wb + 2], in6[c + 2], a0[c]);
                                a1[c] = fmaf(w1r[1][wb],     in6[c],     a1[c]);
                                a1[c] = fmaf(w1r[1][wb + 1], in6[c + 1], a1[c]);
                                a1[c] = fmaf(w1r[1][wb + 2], in6[c + 2], a1[c]);
                            }
                        }
                    // mask (zero-pad semantics) + bias + relu, aligned b128 writes
                    const int gy  = oy - 1 + y;
                    const bool iny = (unsigned)gy < 128u;
                    float4 o0, o1;
                    {
                        const bool i0 = iny && ((unsigned)(ox - 1 + x0 + 0) < 128u);
                        const bool i1 = iny && ((unsigned)(ox - 1 + x0 + 1) < 128u);
                        const bool i2 = iny && ((unsigned)(ox - 1 + x0 + 2) < 128u);
                        const bool i3 = iny && ((unsigned)(ox - 1 + x0 + 3) < 128u);
                        o0.x = i0 ? fmaxf(a0[0] + bb0, 0.f) : 0.f;
                        o0.y = i1 ? fmaxf(a0[1] + bb0, 0.f) : 0.f;
                        o0.z = i2 ? fmaxf(a0[2] + bb0, 0.f) : 0.f;
                        o0.w = i3 ? fmaxf(a0[3] + bb0, 0.f) : 0.f;
                        o1.x = i0 ? fmaxf(a1[0] + bb1, 0.f) : 0.f;
                        o1.y = i1 ? fmaxf(a1[1] + bb1, 0.f) : 0.f;
                        o1.z = i2 ? fmaxf(a1[2] + bb1, 0.f) : 0.f;
                        o1.w = i3 ? fmaxf(a1[3] + bb1, 0.f) : 0.f;
                    }
                    *(float4*)(&c1t[(wvu * 2 + 0) * 648 + y * 36 + x0]) = o0;
                    *(float4*)(&c1t[(wvu * 2 + 1) * 648 + y * 36 + x0]) = o1;
                }
            }
        }
        __syncthreads();   // c1t ready

        // ---- conv2 accumulate over the 8 staged ci ----
        #pragma unroll 1
        for (int s = 0; s < 8; ++s) {
            const int ci = p * 8 + s;
            float win[4][6];
            #pragma unroll
            for (int r = 0; r < 4; ++r) {
                const float* rp = &c1t[s * 648 + (ry0 + r) * 36 + cx4];
                const float4 v4 = *(const float4*)rp;
                const float2 v2 = *(const float2*)(rp + 4);
                win[r][0] = v4.x; win[r][1] = v4.y; win[r][2] = v4.z;
                win[r][3] = v4.w; win[r][4] = v2.x; win[r][5] = v2.y;
            }
            #pragma unroll
            for (int j = 0; j < 8; ++j) {
                const int oc = wvu * 8 + j;                  // uniform
                const float* wp = &w2[(oc * 32 + ci) * 9];   // -> s_load x9
                const float q0 = wp[0], q1 = wp[1], q2 = wp[2],
                            q3 = wp[3], q4 = wp[4], q5 = wp[5],
                            q6 = wp[6], q7 = wp[7], q8 = wp[8];
                #pragma unroll
                for (int r2 = 0; r2 < 2; ++r2)
                    #pragma unroll
                    for (int c2 = 0; c2 < 4; ++c2) {
                        float sum = acc[j][r2 * 4 + c2];
                        sum = fmaf(q0, win[r2][c2],         sum);
                        sum = fmaf(q1, win[r2][c2 + 1],     sum);
                        sum = fmaf(q2, win[r2][c2 + 2],     sum);
                        sum = fmaf(q3, win[r2 + 1][c2],     sum);
                        sum = fmaf(q4, win[r2 + 1][c2 + 1], sum);
                        sum = fmaf(q5, win[r2 + 1][c2 + 2], sum);
                        sum = fmaf(q6, win[r2 + 2][c2],     sum);
                        sum = fmaf(q7, win[r2 + 2][c2 + 1], sum);
                        sum = fmaf(q8, win[r2 + 2][c2 + 2], sum);
                        acc[j][r2 * 4 + c2] = sum;
                    }
            }
        }
    }

    // epilogue: pooled max (2x4 local + partner half via shfl), bias+relu, NHWC
    float full[8];
    #pragma unroll
    for (int j = 0; j < 8; ++j) {
        float mx = acc[j][0];
        #pragma unroll
        for (int v = 1; v < 8; ++v) mx = fmaxf(mx, acc[j][v]);
        const float other = __shfl_xor(mx, 1, 64);
        full[j] = fmaxf(fmaxf(mx, other) + b2[wvu * 8 + j], 0.f);
    }
    const int py = ty * 4 + cy, px = tx * 8 + cx;
    float4 o;
    if (half == 0) o = make_float4(full[0], full[1], full[2], full[3]);
    else           o = make_float4(full[4], full[5], full[6], full[7]);
    *(float4*)(&P1[((b * 32 + py) * 32 + px) * 32 + wvu * 8 + half * 4]) = o;
}

// ---------------------------------------------------------------------------
// Weight repack: OIHW -> [k=(tap*CIN+ci)][oc]   (coalesced GEMM B operand)
// ---------------------------------------------------------------------------
__global__ void k_wrepack(const float* __restrict__ w, float* __restrict__ Wk,
                          int CIN, int COUT)
{
    const int idx = blockIdx.x * 256 + threadIdx.x;
    if (idx >= CIN * COUT * 9) return;
    const int tap = idx / (CIN * COUT);
    const int rem = idx - tap * CIN * COUT;
    const int ci  = rem / COUT;
    const int oc  = rem - ci * COUT;
    Wk[idx] = w[(oc * CIN + ci) * 9 + tap];
}

// ---------------------------------------------------------------------------
// Implicit-GEMM conv3x3 (NHWC): out[m][oc] = sum_k A_im2col[m][k] * Wk[k][oc]
// ---------------------------------------------------------------------------
template<int CIN, int COUT, int HW, int BM, int TM, int TN>
__global__ __launch_bounds__(256, 4)
void k_cgemm(const float* __restrict__ in, const float* __restrict__ Bk,
             const float* __restrict__ bias, float* __restrict__ out)
{
    constexpr int BN = 16 * TN;
    static_assert(BN == COUT, "one n-tile");
    constexpr int SA = (BM == 128) ? 140 : 68;
    constexpr int SB = (BN == 128) ? 140 : 68;
    constexpr int LOG = (HW == 32) ? 5 : 4;
    constexpr int NCH = (CIN * 9) / 32;
    constexpr int AF4 = (BM * 8) / 256;
    constexpr int BF4 = (BN * 8) / 256;

    __shared__ __align__(16) float As[32 * SA];
    __shared__ __align__(16) float Bs[32 * SB];

    const int t  = threadIdx.x;
    const int tm = t >> 4, tn = t & 15;
    const int m0 = blockIdx.x * BM;

    float acc[TM][TN];
    #pragma unroll
    for (int r = 0; r < TM; ++r)
        #pragma unroll
        for (int c = 0; c < TN; ++c) acc[r][c] = 0.f;

    #pragma unroll 1
    for (int ch = 0; ch < NCH; ++ch) {
        if (ch) __syncthreads();
        const int kb  = ch * 32;
        const int tap = kb / CIN;
        const int c0  = kb - tap * CIN;
        const int dy  = tap / 3 - 1, dx = tap - (tap / 3) * 3 - 1;

        #pragma unroll
        for (int j = 0; j < AF4; ++j) {
            const int q    = t + 256 * j;
            const int mrow = q >> 3, c4 = q & 7;
            const int m    = m0 + mrow;
            const int yx   = m & (HW * HW - 1);
            const int b    = m >> (2 * LOG);
            const int y    = yx >> LOG, x = yx & (HW - 1);
            const int iy   = y + dy, ix = x + dx;
            float4 v = make_float4(0.f, 0.f, 0.f, 0.f);
            if ((unsigned)iy < (unsigned)HW && (unsigned)ix < (unsigned)HW)
                v = *(const float4*)(in + ((b * HW + iy) * HW + ix) * CIN + c0 + c4 * 4);
            const int ms = mrow + ((mrow >> 5) << 2);
            As[(c4 * 4 + 0) * SA + ms] = v.x;
            As[(c4 * 4 + 1) * SA + ms] = v.y;
            As[(c4 * 4 + 2) * SA + ms] = v.z;
            As[(c4 * 4 + 3) * SA + ms] = v.w;
        }
        #pragma unroll
        for (int j = 0; j < BF4; ++j) {
            const int q  = t + 256 * j;
            const int kk = q / (BN / 4), n4 = q - kk * (BN / 4);
            float4 v = *(const float4*)(Bk + (kb + kk) * COUT + n4 * 4);
            *(float4*)(&Bs[kk * SB + n4 * 4 + ((n4 >> 3) << 2)]) = v;
        }
        __syncthreads();

        #pragma unroll 2
        for (int kk = 0; kk < 32; ++kk) {
            const float* ap = &As[kk * SA + tm * TM + (((tm * TM) >> 5) << 2)];
            const float* bp = &Bs[kk * SB + tn * TN + (((tn * TN) >> 5) << 2)];
            float a[TM], bb[TN];
            #pragma unroll
            for (int j = 0; j < TM; j += 4) {
                const float4 v = *(const float4*)(ap + j);
                a[j] = v.x; a[j + 1] = v.y; a[j + 2] = v.z; a[j + 3] = v.w;
            }
            #pragma unroll
            for (int j = 0; j < TN; j += 4) {
                const float4 v = *(const float4*)(bp + j);
                bb[j] = v.x; bb[j + 1] = v.y; bb[j + 2] = v.z; bb[j + 3] = v.w;
            }
            #pragma unroll
            for (int r = 0; r < TM; ++r)
                #pragma unroll
                for (int c = 0; c < TN; ++c)
                    acc[r][c] = fmaf(a[r], bb[c], acc[r][c]);
        }
    }

    #pragma unroll
    for (int r = 0; r < TM; ++r) {
        const int m = m0 + tm * TM + r;
        float* op = out + m * COUT + tn * TN;
        #pragma unroll
        for (int c = 0; c < TN; c += 4) {
            float4 v;
            v.x = fmaxf(acc[r][c + 0] + bias[tn * TN + c + 0], 0.f);
            v.y = fmaxf(acc[r][c + 1] + bias[tn * TN + c + 1], 0.f);
            v.z = fmaxf(acc[r][c + 2] + bias[tn * TN + c + 2], 0.f);
            v.w = fmaxf(acc[r][c + 3] + bias[tn * TN + c + 3], 0.f);
            *(float4*)(op + c) = v;
        }
    }
}

// ---------------------------------------------------------------------------
// 2x2 maxpool, NHWC [128][32][32][64] -> [128][16][16][64]
// ---------------------------------------------------------------------------
__global__ __launch_bounds__(256)
void k_pool2(const float* __restrict__ in, float* __restrict__ out)
{
    const int g = blockIdx.x * 256 + threadIdx.x;
    const int c4 = g & 15, xo = (g >> 4) & 15, yo = (g >> 8) & 15, b = g >> 12;
    const float* p = in + ((b * 32 + yo * 2) * 32 + xo * 2) * 64 + c4 * 4;
    const float4 v0 = *(const float4*)(p);
    const float4 v1 = *(const float4*)(p + 64);
    const float4 v2 = *(const float4*)(p + 2048);
    const float4 v3 = *(const float4*)(p + 2112);
    float4 o;
    o.x = fmaxf(fmaxf(v0.x, v1.x), fmaxf(v2.x, v3.x));
    o.y = fmaxf(fmaxf(v0.y, v1.y), fmaxf(v2.y, v3.y));
    o.z = fmaxf(fmaxf(v0.z, v1.z), fmaxf(v2.z, v3.z));
    o.w = fmaxf(fmaxf(v0.w, v1.w), fmaxf(v2.w, v3.w));
    *(float4*)(out + g * 4) = o;
}

// ---------------------------------------------------------------------------
// Split-K FC partial: A[128 x K] @ B[K x 512] -> part[ky][128][512]
// ---------------------------------------------------------------------------
template<int LDA, int KCHUNK, int TN, bool PERM>
__global__ __launch_bounds__(256, 2)
void k_fc_partial(const float* __restrict__ A, const float* __restrict__ Bw,
                  float* __restrict__ part)
{
    constexpr int BN = 16 * TN;
    constexpr int SA = 140;
    constexpr int SB = (BN == 128) ? 140 : 68;
    __shared__ __align__(16) float As[32 * SA];
    __shared__ __align__(16) float Bs[32 * SB];
    const int t  = threadIdx.x;
    const int tm = t >> 4, tn = t & 15;
    const int n0 = blockIdx.x * BN;
    const int k0 = blockIdx.y * KCHUNK;

    float acc[8][TN];
    #pragma unroll
    for (int r = 0; r < 8; ++r)
        #pragma unroll
        for (int c = 0; c < TN; ++c) acc[r][c] = 0.f;

    #pragma unroll 1
    for (int ks = 0; ks < KCHUNK / 32; ++ks) {
        if (ks) __syncthreads();
        const int kb = k0 + ks * 32;
        for (int i = t; i < 4096; i += 256) {
            const int m = i >> 5, kk = i & 31;
            As[kk * SA + m + ((m >> 5) << 2)] = A[m * LDA + kb + kk];
        }
        for (int i = t; i < 32 * BN; i += 256) {
            const int kk = i / BN, n = i - kk * BN;
            const int krow = kb + kk;
            const int kref = PERM ? ((krow & 127) * 256 + (krow >> 7)) : krow;
            Bs[kk * SB + n + ((n >> 5) << 2)] = Bw[kref * 512 + n0 + n];
        }
        __syncthreads();
        #pragma unroll 2
        for (int kk = 0; kk < 32; ++kk) {
            const float* ap = &As[kk * SA + tm * 8 + ((tm >> 2) << 2)];
            const float* bp = &Bs[kk * SB + tn * TN + (((tn * TN) >> 5) << 2)];
            float a[8], bb[TN];
            #pragma unroll
            for (int q = 0; q < 8; q += 4) {
                const float4 v = *(const float4*)(ap + q);
                a[q] = v.x; a[q + 1] = v.y; a[q + 2] = v.z; a[q + 3] = v.w;
            }
            #pragma unroll
            for (int q = 0; q < TN; q += 4) {
                const float4 v = *(const float4*)(bp + q);
                bb[q] = v.x; bb[q + 1] = v.y; bb[q + 2] = v.z; bb[q + 3] = v.w;
            }
            #pragma unroll
            for (int r = 0; r < 8; ++r)
                #pragma unroll
                for (int c = 0; c < TN; ++c)
                    acc[r][c] = fmaf(a[r], bb[c], acc[r][c]);
        }
    }

    const long pb = (long)blockIdx.y * 65536;
    #pragma unroll
    for (int r = 0; r < 8; ++r)
        #pragma unroll
        for (int c = 0; c < TN; ++c)
            part[pb + (tm * 8 + r) * 512 + n0 + tn * TN + c] = acc[r][c];
}

template<int NS>
__global__ __launch_bounds__(256)
void k_fc_reduce(const float* __restrict__ part, const float* __restrict__ bias,
                 float* __restrict__ H)
{
    const int f = (blockIdx.x * 256 + threadIdx.x) * 4;
    const int m = f >> 9, n = f & 511;
    float s0 = 0.f, s1 = 0.f, s2 = 0.f, s3 = 0.f;
    #pragma unroll 4
    for (int q = 0; q < NS; ++q) {
        const float* p = &part[(q * 128 + m) * 512 + n];
        s0 += p[0]; s1 += p[1]; s2 += p[2]; s3 += p[3];
    }
    H[f]     = fmaxf(s0 + bias[n],     0.f);
    H[f + 1] = fmaxf(s1 + bias[n + 1], 0.f);
    H[f + 2] = fmaxf(s2 + bias[n + 2], 0.f);
    H[f + 3] = fmaxf(s3 + bias[n + 3], 0.f);
}

// ---------------------------------------------------------------------------
// Final: FC3 + sampling + patch gather
// ---------------------------------------------------------------------------
__device__ __forceinline__ float softplusf(float x) {
    return (x > 20.f) ? x : log1pf(expf(x));
}
__device__ __forceinline__ float sigmoidf_(float x) {
    return 1.f / (1.f + expf(-x));
}

__global__ __launch_bounds__(256)
void k_final(const float* __restrict__ H2, const float* __restrict__ wl3,
             const float* __restrict__ bl3, const float* __restrict__ noise,
             const float* __restrict__ img, float* __restrict__ outp)
{
    __shared__ float h2[512];
    __shared__ float red[144];
    __shared__ float prep[36];
    __shared__ int ptsh[12], ptsw[12];
    const int b = blockIdx.x, t = threadIdx.x;

    h2[t]       = H2[b * 512 + t];
    h2[t + 256] = H2[b * 512 + 256 + t];
    __syncthreads();

    if (t < 144) {
        const int n = t >> 2, q = t & 3;
        float s = 0.f;
        for (int k = q * 128; k < q * 128 + 128; ++k)
            s = fmaf(h2[k], wl3[k * 36 + n], s);
        red[t] = s;
    }
    __syncthreads();
    if (t < 36)
        prep[t] = red[t * 4] + red[t * 4 + 1] + red[t * 4 + 2] + red[t * 4 + 3] + bl3[t];
    __syncthreads();

    if (t < 12) {
        const float m0 = prep[t * 3], m1 = prep[t * 3 + 1], sv = prep[t * 3 + 2];
        const float sig = softplusf(sv + 2.0f) * 128.f + 1e-7f;
        const float n0 = noise[(b * 12 + t) * 2], n1 = noise[(b * 12 + t) * 2 + 1];
        const float sa0 = m0 + sig * n0;
        const float sa1 = m1 + sig * n1;
        int p0 = (int)rintf(sigmoidf_(sa0) * 111.f);
        int p1 = (int)rintf(sigmoidf_(sa1) * 111.f);
        p0 = min(max(p0, 0), 111);
        p1 = min(max(p1, 0), 111);
        const int RM = 1179648;
        outp[RM        + (b * 12 + t) * 2 + 0] = m0;
        outp[RM        + (b * 12 + t) * 2 + 1] = m1;
        outp[RM + 3072 + (b * 12 + t) * 2 + 0] = sig;
        outp[RM + 3072 + (b * 12 + t) * 2 + 1] = sig;
        outp[RM + 6144 + (b * 12 + t) * 2 + 0] = sa0;
        outp[RM + 6144 + (b * 12 + t) * 2 + 1] = sa1;
        ptsh[t] = p0;
        ptsw[t] = p1;
    }
    __syncthreads();

    for (int i = t; i < 9216; i += 256) {
        const int g  = i / 768, r = i - g * 768;
        const int c  = r >> 8, r2 = r & 255;
        const int y  = r2 >> 4, x = r2 & 15;
        outp[b * 9216 + i] = img[((b * 3 + c) * 128 + ptsh[g] + y) * 128 + (ptsw[g] + x)];
    }
}

// ---------------------------------------------------------------------------
extern "C" void kernel_launch(void* const* d_in, const int* in_sizes, int n_in,
                              void* d_out, int out_size, void* d_ws, size_t ws_size,
                              hipStream_t stream)
{
    const float* img  = (const float*)d_in[0];
    const float* nois = (const float*)d_in[1];
    const float* w1 = (const float*)d_in[2];  const float* b1 = (const float*)d_in[3];
    const float* w2 = (const float*)d_in[4];  const float* b2 = (const float*)d_in[5];
    const float* w3 = (const float*)d_in[6];  const float* b3 = (const float*)d_in[7];
    const float* w4 = (const float*)d_in[8];  const float* b4 = (const float*)d_in[9];
    const float* w5 = (const float*)d_in[10]; const float* b5 = (const float*)d_in[11];
    const float* w6 = (const float*)d_in[12]; const float* b6 = (const float*)d_in[13];
    const float* wl1 = (const float*)d_in[14]; const float* bl1 = (const float*)d_in[15];
    const float* wl2 = (const float*)d_in[16]; const float* bl2 = (const float*)d_in[17];
    const float* wl3 = (const float*)d_in[18]; const float* bl3 = (const float*)d_in[19];
    float* out = (float*)d_out;
    float* ws  = (float*)d_ws;

    float* P1   = ws;                    // [128][32][32][32] NHWC
    float* P2   = ws;                    // [128][16][16][64] NHWC (aliases P1)
    float* A3   = ws + 4194304;          // [128][32][32][64] NHWC
    float* A4f  = ws + 12582912;         // [128][32][32][64] NHWC
    float* A5   = ws + 12582912;         // [128][16][16][128] NHWC (aliases A4f)
    float* A6   = ws + 16777216;         // [128][16][16][128] NHWC
    float* FP1  = ws + 20971520;         // [64][128][512]
    float* H1   = ws + 25165824;         // [128][512]
    float* FP2  = ws + 25231360;         // [16][128][512]
    float* H2   = ws + 26279936;         // [128][512]
    float* Wk3  = ws + 26345472;         // [288][64]
    float* Wk4  = ws + 26363904;         // [576][64]
    float* Wk5  = ws + 26400768;         // [576][128]
    float* Wk6  = ws + 26474496;         // [1152][128]

    hipLaunchKernelGGL(k_wrepack, dim3(72),  dim3(256), 0, stream, w3, Wk3, 32, 64);
    hipLaunchKernelGGL(k_wrepack, dim3(144), dim3(256), 0, stream, w4, Wk4, 64, 64);
    hipLaunchKernelGGL(k_wrepack, dim3(288), dim3(256), 0, stream, w5, Wk5, 64, 128);
    hipLaunchKernelGGL(k_wrepack, dim3(576), dim3(256), 0, stream, w6, Wk6, 128, 128);

    hipLaunchKernelGGL(k_conv12, dim3(32, 128), dim3(256), 0, stream,
                       img, w1, b1, w2, b2, P1);
    hipLaunchKernelGGL((k_cgemm<32, 64, 32, 128, 8, 4>), dim3(1024), dim3(256), 0, stream,
                       P1, Wk3, b3, A3);
    hipLaunchKernelGGL((k_cgemm<64, 64, 32, 128, 8, 4>), dim3(1024), dim3(256), 0, stream,
                       A3, Wk4, b4, A4f);
    hipLaunchKernelGGL(k_pool2, dim3(2048), dim3(256), 0, stream, A4f, P2);
    hipLaunchKernelGGL((k_cgemm<64, 128, 16, 64, 4, 8>), dim3(512), dim3(256), 0, stream,
                       P2, Wk5, b5, A5);
    hipLaunchKernelGGL((k_cgemm<128, 128, 16, 64, 4, 8>), dim3(512), dim3(256), 0, stream,
                       A5, Wk6, b6, A6);
    hipLaunchKernelGGL((k_fc_partial<32768, 512, 4, true>), dim3(8, 64), dim3(256), 0, stream,
                       A6, wl1, FP1);
    hipLaunchKernelGGL(k_fc_reduce<64>, dim3(64), dim3(256), 0, stream, FP1, bl1, H1);
    hipLaunchKernelGGL((k_fc_partial<512, 32, 4, false>), dim3(8, 16), dim3(256), 0, stream,
                       H1, wl2, FP2);
    hipLaunchKernelGGL(k_fc_reduce<16>, dim3(64), dim3(256), 0, stream, FP2, bl2, H2);
    hipLaunchKernelGGL(k_final, dim3(128), dim3(256), 0, stream,
                       H2, wl3, bl3, nois, img, out);
}